// Round 4
// baseline (38.008 us; speedup 1.0000x reference)
//
#include <hip/hip_runtime.h>

#define HID 16
#define NPT 4   // nodes per thread

typedef float vfloat4 __attribute__((ext_vector_type(4)));

__global__ __launch_bounds__(256) void mpainn_energy4_kernel(
    const float* __restrict__ x,
    const int* __restrict__ batch,
    const float* __restrict__ w1,
    const float* __restrict__ b1,
    const float* __restrict__ w2,
    const float* __restrict__ b2,
    float* __restrict__ out,   // [E (G floats) | F (3N floats)]
    int n, int G)
{
    __shared__ float w1s[HID * HID];
    __shared__ float b1s[HID];
    __shared__ float w2s[HID];
    __shared__ float b2s;

    const int tid = threadIdx.x;
    if (tid < HID * HID) w1s[tid] = w1[tid];
    if (tid < HID) { b1s[tid] = b1[tid]; w2s[tid] = w2[tid]; }
    if (tid == 0) b2s = b2[0];
    __syncthreads();

    const long long gid = (long long)blockIdx.x * blockDim.x + tid;
    const long long i0 = NPT * gid;
    const int lane = tid & 63;

    // ---- zero the F_hat region (grad wrt pos is exactly 0) ----
    float* __restrict__ F = out + G;
    if (i0 + NPT - 1 < n) {
        const vfloat4 z = {0.f, 0.f, 0.f, 0.f};
        vfloat4* fp = (vfloat4*)(F + 3 * NPT * gid);   // 48B, 16B-aligned
        __builtin_nontemporal_store(z, fp);
        __builtin_nontemporal_store(z, fp + 1);
        __builtin_nontemporal_store(z, fp + 2);
    } else {
        for (long long i = i0; i < n; ++i) {
            F[3 * i] = 0.f; F[3 * i + 1] = 0.f; F[3 * i + 2] = 0.f;
        }
    }

    // ---- batch keys ----
    int bk[NPT];
    if (i0 + NPT - 1 < n) {
        const int4 bb = *(const int4*)(batch + i0);
        bk[0] = bb.x; bk[1] = bb.y; bk[2] = bb.z; bk[3] = bb.w;
    } else {
        #pragma unroll
        for (int t = 0; t < NPT; ++t) bk[t] = (i0 + t < n) ? batch[i0 + t] : -1;
    }

    // ---- load x[i, 48:64] for NPT nodes ----
    float s[NPT][16];
    #pragma unroll
    for (int t = 0; t < NPT; ++t) {
        const long long i = i0 + t;
        if (i < n) {
            const float4* p = (const float4*)(x + i * 64 + 48);
            const float4 v0 = p[0], v1 = p[1], v2 = p[2], v3 = p[3];
            s[t][0]=v0.x; s[t][1]=v0.y; s[t][2]=v0.z; s[t][3]=v0.w;
            s[t][4]=v1.x; s[t][5]=v1.y; s[t][6]=v1.z; s[t][7]=v1.w;
            s[t][8]=v2.x; s[t][9]=v2.y; s[t][10]=v2.z; s[t][11]=v2.w;
            s[t][12]=v3.x; s[t][13]=v3.y; s[t][14]=v3.z; s[t][15]=v3.w;
        } else {
            #pragma unroll
            for (int j = 0; j < 16; ++j) s[t][j] = 0.f;
        }
    }

    // ---- MLP, k-outer so each w1 row is read from LDS once per wave ----
    float h[NPT][16];
    #pragma unroll
    for (int t = 0; t < NPT; ++t)
        #pragma unroll
        for (int j = 0; j < 16; ++j) h[t][j] = b1s[j];

    #pragma unroll
    for (int k = 0; k < 16; ++k) {
        float wk[16];
        #pragma unroll
        for (int j = 0; j < 16; ++j) wk[j] = w1s[k * 16 + j];
        #pragma unroll
        for (int t = 0; t < NPT; ++t) {
            const float sk = s[t][k];
            #pragma unroll
            for (int j = 0; j < 16; ++j) h[t][j] += sk * wk[j];
        }
    }

    float e[NPT];
    #pragma unroll
    for (int t = 0; t < NPT; ++t) {
        float acc = b2s;
        #pragma unroll
        for (int j = 0; j < 16; ++j) {
            const float a = h[t][j];
            const float sig = 1.0f / (1.0f + __expf(-a));
            acc += (a * sig) * w2s[j];
        }
        e[t] = acc;
    }

    // ---- segmented reduction (batch sorted) ----
    // Trailing run (key bk[3]) goes through the wave segmented scan;
    // runs that end inside this thread are flushed directly (with the
    // incoming prefix from the scan when the first run extends backward).
    const int k3 = bk[NPT - 1];
    float v = e[3];
    if (bk[2] == k3) { v += e[2]; if (bk[1] == bk[2]) { v += e[1]; if (bk[0] == bk[1]) v += e[0]; } }

    #pragma unroll
    for (int d = 1; d < 64; d <<= 1) {
        const float ov = __shfl_up(v, (unsigned)d, 64);
        const int   ok = __shfl_up(k3, (unsigned)d, 64);
        if (lane >= d && ok == k3) v += ov;
    }

    const float pv = __shfl_up(v, 1, 64);
    const int   pk = __shfl_up(k3, 1, 64);

    float acc = (lane > 0 && pk == bk[0]) ? pv : 0.f;
    acc += e[0];
    if (bk[0] != bk[1]) { if (bk[0] >= 0) atomicAdd(&out[bk[0]], acc); acc = 0.f; }
    acc += e[1];
    if (bk[1] != bk[2]) { if (bk[1] >= 0) atomicAdd(&out[bk[1]], acc); acc = 0.f; }
    acc += e[2];
    if (bk[2] != k3)    { if (bk[2] >= 0) atomicAdd(&out[bk[2]], acc); }
    // trailing acc is represented by v — do not flush here.

    const int nb0 = __shfl_down(bk[0], 1, 64);
    const bool last = (lane == 63) || (nb0 != k3);
    if (k3 >= 0 && last) atomicAdd(&out[k3], v);
}

extern "C" void kernel_launch(void* const* d_in, const int* in_sizes, int n_in,
                              void* d_out, int out_size, void* d_ws, size_t ws_size,
                              hipStream_t stream)
{
    const float* x     = (const float*)d_in[0];
    // d_in[1] = pos (unused: energy() ignores p, so F_hat == 0)
    const int*   batch = (const int*)d_in[2];
    // d_in[3] = num_graphs scalar
    const float* w1    = (const float*)d_in[4];
    const float* b1    = (const float*)d_in[5];
    const float* w2    = (const float*)d_in[6];
    const float* b2    = (const float*)d_in[7];

    const int n = in_sizes[2];          // N = 1,000,000
    const int G = out_size - 3 * n;     // 8192
    float* out = (float*)d_out;

    // Zero only the E region (32 KB); F region is written by the kernel.
    (void)hipMemsetAsync(d_out, 0, (size_t)G * sizeof(float), stream);

    const long long threads = ((long long)n + NPT - 1) / NPT;
    const int block = 256;
    const int grid = (int)((threads + block - 1) / block);
    mpainn_energy4_kernel<<<grid, block, 0, stream>>>(x, batch, w1, b1, w2, b2, out, n, G);
}